// Round 3
// baseline (274.943 us; speedup 1.0000x reference)
//
#include <hip/hip_runtime.h>
#include <math.h>

#define N_TOK 4096
#define DM 512

typedef _Float16 f16x8 __attribute__((ext_vector_type(8)));
typedef _Float16 f16x4 __attribute__((ext_vector_type(4)));
typedef float f32x4 __attribute__((ext_vector_type(4)));

__device__ __forceinline__ void async_ld16(const ushort* g, ushort* l) {
  __builtin_amdgcn_global_load_lds(
      (const __attribute__((address_space(1))) void*)g,
      (__attribute__((address_space(3))) void*)l, 16, 0, 0);
}

template <int N>
__device__ __forceinline__ void vm_wait() {
  asm volatile("s_waitcnt vmcnt(%0)" ::"i"(N) : "memory");
}

// ---------------------------------------------------------------------------
// Fused pack + sigma.
// blocks [0,2048): pack x (1024 elems = rows 2b,2b+1) and compute sigma rows
// blocks [2048,2816): pack Wq|Wk|Wv into concatenated Wc16
// ---------------------------------------------------------------------------
__global__ __launch_bounds__(256) void pack_sigma(
    const float* __restrict__ x, const float* __restrict__ Wq,
    const float* __restrict__ Wk, const float* __restrict__ Wv,
    const float* __restrict__ Ws, _Float16* __restrict__ x16,
    _Float16* __restrict__ Wc16, float* __restrict__ sg) {
  const int b = blockIdx.x;
  const int t = threadIdx.x;
  if (b < 2048) {
    int i = b * 1024 + t * 4;
    float4 v = *(const float4*)&x[i];
    f16x4 o;
    o.x = (_Float16)v.x; o.y = (_Float16)v.y;
    o.z = (_Float16)v.z; o.w = (_Float16)v.w;
    *(f16x4*)&x16[i] = o;
    // sigma: threads [0,128) -> row 2b, [128,256) -> row 2b+1
    int col = (t * 4) & 511;
    float4 w = *(const float4*)&Ws[col];
    float p = v.x * w.x + v.y * w.y + v.z * w.z + v.w * w.w;
    __shared__ float red[256];
    red[t] = p;
    __syncthreads();
    int lt = t & 127;
    for (int off = 64; off > 0; off >>= 1) {
      if (lt < off) red[t] += red[t + off];
      __syncthreads();
    }
    if (lt == 0) {
      float s = red[t];
      sg[2 * b + (t >> 7)] = fminf(fmaxf(s, 0.001f), 1.0f);
    }
  } else {
    int e = (b - 2048) * 1024 + t * 4;
    const float* src;
    int le = e & (DM * DM - 1);
    if (e < DM * DM) src = Wq + le;
    else if (e < 2 * DM * DM) src = Wk + le;
    else src = Wv + le;
    float4 v = *(const float4*)src;
    f16x4 o;
    o.x = (_Float16)v.x; o.y = (_Float16)v.y;
    o.z = (_Float16)v.z; o.w = (_Float16)v.w;
    *(f16x4*)&Wc16[e] = o;
  }
}

// ---------------------------------------------------------------------------
// 3-deep pipelined fp16 MFMA NT GEMM: C[m,n] = scale * sum_k A[m,k]*B[n,k]
// 256 thr = 4 waves in 2x2 grid; wave tile (BM/2)x(BN/2).
// 3 LDS buffers; counted vmcnt, raw s_barrier (as R2 — verified).
// EPI=1: QKV fused (N=1536): region bn>>9: 0->D0 (Q16), 1->D1 (K16),
//        2-> LDS-transpose -> D2 = VT16 [512][4096]  (V16 never materialized)
// EPI=3: raw scores: D0[gr*N_TOK+gc] = (f16)(acc*scale), PLUS per-row
//        softmax partials over this block's 128 cols:
//        Part[row*32 + blockIdx.x] = (m_b, l_b)  (float2)
// ---------------------------------------------------------------------------
template <int BM, int BN, int BK, int NT, int EPI>
__global__ __launch_bounds__(256) void gemm_pipe(
    const _Float16* __restrict__ A, int lda, const _Float16* __restrict__ B,
    int ldb, float scale, _Float16* __restrict__ D0,
    _Float16* __restrict__ D1, _Float16* __restrict__ D2,
    float2* __restrict__ Part) {
  constexpr int TB = (BM + BN) * BK;  // f16 per LDS buffer
  constexpr int ACH = BM * BK / 8;    // A 16B-chunks per tile
  constexpr int BCH = BN * BK / 8;
  constexpr int L = (ACH + BCH) / 256;  // global_load_lds per thread per tile
  constexpr int MI = BM / 32;
  constexpr int NJ = BN / 32;
  __shared__ _Float16 lds[3 * TB];
  const int t = threadIdx.x;

  const int w = t >> 6, Ln = t & 63;
  const int wm = (w >> 1) * (BM / 2), wn = (w & 1) * (BN / 2);
  const int row = Ln & 15, quad = Ln >> 4;
  const int bm = blockIdx.y * BM, bn = blockIdx.x * BN;

  f32x4 acc[MI][NJ] = {{}};

  const ushort* gp[L];
#pragma unroll
  for (int k = 0; k < L; ++k) {
    int c = t + k * 256;
    if (c < ACH) {
      int r = c / (BK / 8), c8 = c % (BK / 8);
      gp[k] = (const ushort*)(A + (size_t)(bm + r) * lda + c8 * 8);
    } else {
      int cb = c - ACH;
      int r = cb / (BK / 8), c8 = cb % (BK / 8);
      gp[k] = (const ushort*)(B + (size_t)(bn + r) * ldb + c8 * 8);
    }
  }

  auto stage = [&](int buf) {
    _Float16* dst = lds + buf * TB;
#pragma unroll
    for (int k = 0; k < L; ++k) {
      async_ld16(gp[k], (ushort*)(dst + (t + k * 256) * 8));
      gp[k] += BK;
    }
  };

  stage(0);
  stage(1);

  for (int tt = 0; tt < NT; ++tt) {
    const int cur = tt % 3;
    if (tt + 2 < NT) stage((tt + 2) % 3);
    if (tt < NT - 2) vm_wait<2 * L>();
    else if (tt == NT - 2) vm_wait<L>();
    else vm_wait<0>();
    __builtin_amdgcn_s_barrier();

    const _Float16* Ah = lds + cur * TB;
    const _Float16* Bh = Ah + BM * BK;
    f16x8 af[BK / 32][MI], bf[BK / 32][NJ];
#pragma unroll
    for (int kk = 0; kk < BK / 32; ++kk) {
#pragma unroll
      for (int i = 0; i < MI; ++i)
        af[kk][i] =
            *(const f16x8*)&Ah[(wm + i * 16 + row) * BK + kk * 32 + quad * 8];
#pragma unroll
      for (int j = 0; j < NJ; ++j)
        bf[kk][j] =
            *(const f16x8*)&Bh[(wn + j * 16 + row) * BK + kk * 32 + quad * 8];
    }
#pragma unroll
    for (int kk = 0; kk < BK / 32; ++kk)
#pragma unroll
      for (int i = 0; i < MI; ++i)
#pragma unroll
        for (int j = 0; j < NJ; ++j)
          acc[i][j] = __builtin_amdgcn_mfma_f32_16x16x32_f16(
              af[kk][i], bf[kk][j], acc[i][j], 0, 0, 0);

    asm volatile("s_waitcnt lgkmcnt(0)" ::: "memory");
    __builtin_amdgcn_s_barrier();
  }

  // epilogue: C/D layout col = lane&15, row = quad*4 + reg
  if constexpr (EPI == 1) {
    const int region = bn >> 9;  // uniform per block
    if (region < 2) {
      _Float16* D = (region == 0) ? D0 : D1;
#pragma unroll
      for (int i = 0; i < MI; ++i)
#pragma unroll
        for (int j = 0; j < NJ; ++j)
#pragma unroll
          for (int r = 0; r < 4; ++r) {
            int gr = bm + wm + i * 16 + quad * 4 + r;
            int nn = (bn & 511) + wn + j * 16 + row;
            D[(size_t)gr * 512 + nn] = (_Float16)acc[i][j][r];
          }
    } else {
      // V region: transpose via LDS, write VT16[nn][token] coalesced.
      _Float16* T = lds;  // [128][136] f16 = 34 KB (pipeline done, lds free)
#pragma unroll
      for (int i = 0; i < MI; ++i)
#pragma unroll
        for (int j = 0; j < NJ; ++j) {
          int nn = wn + j * 16 + row;
          int gr0 = wm + i * 16 + quad * 4;
          f16x4 v;
          v.x = (_Float16)acc[i][j][0]; v.y = (_Float16)acc[i][j][1];
          v.z = (_Float16)acc[i][j][2]; v.w = (_Float16)acc[i][j][3];
          *(f16x4*)&T[nn * 136 + gr0] = v;
        }
      __syncthreads();
#pragma unroll
      for (int c = 0; c < 8; ++c) {
        int cc = t + c * 256;        // 2048 chunks
        int nn = cc >> 4;            // 0..127
        int g8 = (cc & 15) * 8;      // 0..120
        f16x8 v = *(const f16x8*)&T[nn * 136 + g8];
        *(f16x8*)&D2[(size_t)((bn & 511) + nn) * 4096 + bm + g8] = v;
      }
    }
  } else {
    // EPI==3: raw scores + per-row (m,l) partials over this block's cols
    float2* Ml = (float2*)lds;  // [2][BM]  (lds free after final barrier)
#pragma unroll
    for (int i = 0; i < MI; ++i)
#pragma unroll
      for (int r = 0; r < 4; ++r) {
        float sv[NJ];
        int gr = bm + wm + i * 16 + quad * 4 + r;
#pragma unroll
        for (int j = 0; j < NJ; ++j) {
          _Float16 h = (_Float16)(acc[i][j][r] * scale);
          D0[(size_t)gr * N_TOK + bn + wn + j * 16 + row] = h;
          sv[j] = (float)h;  // stats from fp16-rounded values (bit-compat)
        }
        float m = sv[0];
#pragma unroll
        for (int j = 1; j < NJ; ++j) m = fmaxf(m, sv[j]);
#pragma unroll
        for (int off = 1; off < 16; off <<= 1)
          m = fmaxf(m, __shfl_xor(m, off));
        float se = 0.f;
#pragma unroll
        for (int j = 0; j < NJ; ++j) se += __expf(sv[j] - m);
#pragma unroll
        for (int off = 1; off < 16; off <<= 1) se += __shfl_xor(se, off);
        if (row == 0) {
          int rb = wm + i * 16 + quad * 4 + r;  // 0..BM-1
          Ml[(w & 1) * BM + rb] = make_float2(m, se);
        }
      }
    __syncthreads();
    // combine the two col-half waves, write global partials
    {
      float2 a = Ml[t];
      float2 b2 = Ml[BM + t];
      float m = fmaxf(a.x, b2.x);
      float l = a.y * __expf(a.x - m) + b2.y * __expf(b2.x - m);
      Part[(size_t)(bm + t) * 32 + blockIdx.x] = make_float2(m, l);
    }
  }
}

// ---------------------------------------------------------------------------
// Mega tail dispatch:
//  b in [0,256)        : Z tile = softmax(Sc) @ V   (BM=64, BN=128, BK=64,
//                        3-deep pipeline; p = exp(s-m)/l applied on A-frags)
//  b in [256,512)      : S-writer, 16 rows each: S = exp(s-m)/l  (fp32)
//  b in [512,1536)     : P rows (4 each)            [WITH_P only]
// ---------------------------------------------------------------------------
template <int WITH_P>
__global__ __launch_bounds__(256) void sv_fused(
    const _Float16* __restrict__ Sc, const float2* __restrict__ stats,
    const _Float16* __restrict__ VT, float* __restrict__ Z,
    float* __restrict__ S, const float* __restrict__ sigma,
    float* __restrict__ P) {
  constexpr int BM = 64, BN = 128, BK = 64, NT = N_TOK / BK;
  constexpr int TB = (BM + BN) * BK;    // 12288 f16
  constexpr int ACH = BM * BK / 8;      // 512
  constexpr int L = (ACH + BN * BK / 8) / 256;  // 6
  __shared__ _Float16 lds[3 * TB];
  const int t = threadIdx.x;
  const int b = blockIdx.x;

  if (WITH_P && b >= 512) {
    // ---------------- P rows (4 per block) ----------------
    float* red = (float*)lds;
    const int pidx = b - 512;  // 0..1023
    const int wv = t >> 6, lane = t & 63;
#pragma unroll 1
    for (int rr = 0; rr < 4; ++rr) {
      const int i = pidx * 4 + rr;
      const float sgv = sigma[i];
      const float inv2 = -0.5f / (sgv * sgv);
      const float cc = rsqrtf(6.283185307179586f * sgv);
      float4 g[4];
      float sum = 0.f;
#pragma unroll
      for (int r = 0; r < 4; ++r) {
        int j = r * 1024 + t * 4;
        float d0 = (float)(i - j);
        float d1 = d0 - 1.f, d2 = d0 - 2.f, d3 = d0 - 3.f;
        g[r].x = __expf(inv2 * d0 * d0) * cc;
        g[r].y = __expf(inv2 * d1 * d1) * cc;
        g[r].z = __expf(inv2 * d2 * d2) * cc;
        g[r].w = __expf(inv2 * d3 * d3) * cc;
        sum += g[r].x + g[r].y + g[r].z + g[r].w;
      }
#pragma unroll
      for (int off = 32; off > 0; off >>= 1) sum += __shfl_xor(sum, off);
      if (lane == 0) red[wv] = sum;
      __syncthreads();
      const float inv = 1.0f / (red[0] + red[1] + red[2] + red[3] + 1e-8f);
      float* Prow = P + (size_t)i * N_TOK;
#pragma unroll
      for (int r = 0; r < 4; ++r) {
        g[r].x *= inv; g[r].y *= inv; g[r].z *= inv; g[r].w *= inv;
        *(float4*)&Prow[r * 1024 + t * 4] = g[r];
      }
      __syncthreads();
    }
    return;
  }

  if (b >= 256) {
    // ---------------- S-writer: rows [rs, rs+16) ----------------
    const int rs = (b - 256) * 16;
    float2* pm = (float2*)lds;          // [256] partial combine
    float* sm = (float*)(pm + 256);     // [16] m
    float* si = sm + 16;                // [16] 1/l
    {
      int rr = t >> 4, kh = t & 15;
      float2 p0 = stats[(size_t)(rs + rr) * 32 + 2 * kh];
      float2 p1 = stats[(size_t)(rs + rr) * 32 + 2 * kh + 1];
      float m = fmaxf(p0.x, p1.x);
      float l = p0.y * __expf(p0.x - m) + p1.y * __expf(p1.x - m);
      pm[t] = make_float2(m, l);
    }
    __syncthreads();
    if (t < 16) {
      float m = -INFINITY, l = 0.f;
#pragma unroll
      for (int k = 0; k < 16; ++k) {
        float2 pr = pm[t * 16 + k];
        float nm = fmaxf(m, pr.x);
        l = l * __expf(m - nm) + pr.y * __expf(pr.x - nm);
        m = nm;
      }
      sm[t] = m;
      si[t] = 1.0f / l;
    }
    __syncthreads();
#pragma unroll 1
    for (int r = 0; r < 16; ++r) {
      const int rowg = rs + r;
      const float m = sm[r], linv = si[r];
      const _Float16* src = Sc + (size_t)rowg * N_TOK + t * 16;
      float* dst = S + (size_t)rowg * N_TOK + t * 16;
      f16x8 h0 = *(const f16x8*)src;
      f16x8 h1 = *(const f16x8*)(src + 8);
      float4 o0, o1, o2, o3;
      o0.x = __expf((float)h0[0] - m) * linv;
      o0.y = __expf((float)h0[1] - m) * linv;
      o0.z = __expf((float)h0[2] - m) * linv;
      o0.w = __expf((float)h0[3] - m) * linv;
      o1.x = __expf((float)h0[4] - m) * linv;
      o1.y = __expf((float)h0[5] - m) * linv;
      o1.z = __expf((float)h0[6] - m) * linv;
      o1.w = __expf((float)h0[7] - m) * linv;
      o2.x = __expf((float)h1[0] - m) * linv;
      o2.y = __expf((float)h1[1] - m) * linv;
      o2.z = __expf((float)h1[2] - m) * linv;
      o2.w = __expf((float)h1[3] - m) * linv;
      o3.x = __expf((float)h1[4] - m) * linv;
      o3.y = __expf((float)h1[5] - m) * linv;
      o3.z = __expf((float)h1[6] - m) * linv;
      o3.w = __expf((float)h1[7] - m) * linv;
      *(float4*)(dst + 0) = o0;
      *(float4*)(dst + 4) = o1;
      *(float4*)(dst + 8) = o2;
      *(float4*)(dst + 12) = o3;
    }
    return;
  }

  // ---------------- SV GEMM: Z[bm:bm+64][bn:bn+128] ----------------
  const int w = t >> 6, Ln = t & 63;
  const int wm = (w >> 1) * 32, wn = (w & 1) * 64;
  const int row = Ln & 15, quad = Ln >> 4;
  const int bm = (b >> 2) * BM, bn = (b & 3) * BN;

  // per-lane softmax stats for this lane's A-frag rows (row = lane&15)
  float mrow[2], linv[2];
#pragma unroll
  for (int i = 0; i < 2; ++i) {
    const int gr = bm + wm + i * 16 + row;
    float m = -INFINITY, l = 0.f;
#pragma unroll
    for (int kb = 0; kb < 32; ++kb) {
      float2 pr = stats[(size_t)gr * 32 + kb];
      float nm = fmaxf(m, pr.x);
      l = l * __expf(m - nm) + pr.y * __expf(pr.x - nm);
      m = nm;
    }
    mrow[i] = m;
    linv[i] = 1.0f / l;
  }

  f32x4 acc[2][4] = {{}};

  const ushort* gp[L];
#pragma unroll
  for (int k = 0; k < L; ++k) {
    int c = t + k * 256;
    if (c < ACH) {
      int r = c >> 3, c8 = c & 7;
      gp[k] = (const ushort*)(Sc + (size_t)(bm + r) * N_TOK + c8 * 8);
    } else {
      int cb = c - ACH;
      int r = cb >> 3, c8 = cb & 7;
      gp[k] = (const ushort*)(VT + (size_t)(bn + r) * N_TOK + c8 * 8);
    }
  }
  auto stage = [&](int buf) {
    _Float16* dst = lds + buf * TB;
#pragma unroll
    for (int k = 0; k < L; ++k) {
      async_ld16(gp[k], (ushort*)(dst + (t + k * 256) * 8));
      gp[k] += BK;
    }
  };

  stage(0);
  stage(1);

  for (int tt = 0; tt < NT; ++tt) {
    const int cur = tt % 3;
    if (tt + 2 < NT) stage((tt + 2) % 3);
    if (tt < NT - 2) vm_wait<2 * L>();
    else if (tt == NT - 2) vm_wait<L>();
    else vm_wait<0>();
    __builtin_amdgcn_s_barrier();

    const _Float16* Ah = lds + cur * TB;
    const _Float16* Bh = Ah + BM * BK;
    f16x8 af[2][2], bf[2][4];
#pragma unroll
    for (int kk = 0; kk < 2; ++kk) {
#pragma unroll
      for (int i = 0; i < 2; ++i) {
        f16x8 raw = *(const f16x8*)&Ah[(wm + i * 16 + row) * BK + kk * 32 +
                                       quad * 8];
        f16x8 pa;
#pragma unroll
        for (int e = 0; e < 8; ++e)
          pa[e] = (_Float16)(__expf((float)raw[e] - mrow[i]) * linv[i]);
        af[kk][i] = pa;
      }
#pragma unroll
      for (int j = 0; j < 4; ++j)
        bf[kk][j] =
            *(const f16x8*)&Bh[(wn + j * 16 + row) * BK + kk * 32 + quad * 8];
    }
#pragma unroll
    for (int kk = 0; kk < 2; ++kk)
#pragma unroll
      for (int i = 0; i < 2; ++i)
#pragma unroll
        for (int j = 0; j < 4; ++j)
          acc[i][j] = __builtin_amdgcn_mfma_f32_16x16x32_f16(
              af[kk][i], bf[kk][j], acc[i][j], 0, 0, 0);

    asm volatile("s_waitcnt lgkmcnt(0)" ::: "memory");
    __builtin_amdgcn_s_barrier();
  }

#pragma unroll
  for (int i = 0; i < 2; ++i)
#pragma unroll
    for (int j = 0; j < 4; ++j)
#pragma unroll
      for (int r = 0; r < 4; ++r) {
        int gr = bm + wm + i * 16 + quad * 4 + r;
        int gc = bn + wn + j * 16 + row;
        Z[(size_t)gr * DM + gc] = acc[i][j][r];
      }
}

// ---------------------------------------------------------------------------
// Fallback P-only tail (used only if ws too small to relocate staging)
// ---------------------------------------------------------------------------
__global__ __launch_bounds__(256) void tailP(const float* __restrict__ sigma,
                                             float* __restrict__ P) {
  __shared__ float red[256];
  const int t = threadIdx.x;
  const int i = blockIdx.x;
  const float sg = sigma[i];
  const float inv2 = -0.5f / (sg * sg);
  const float c = rsqrtf(6.283185307179586f * sg);
  float4 g[4];
  float sum = 0.f;
#pragma unroll
  for (int r = 0; r < 4; ++r) {
    int j = r * 1024 + t * 4;
    float d0 = (float)(i - j);
    float d1 = d0 - 1.f, d2 = d0 - 2.f, d3 = d0 - 3.f;
    g[r].x = __expf(inv2 * d0 * d0) * c;
    g[r].y = __expf(inv2 * d1 * d1) * c;
    g[r].z = __expf(inv2 * d2 * d2) * c;
    g[r].w = __expf(inv2 * d3 * d3) * c;
    sum += g[r].x + g[r].y + g[r].z + g[r].w;
  }
  red[t] = sum;
  __syncthreads();
  for (int off = 128; off > 0; off >>= 1) {
    if (t < off) red[t] += red[t + off];
    __syncthreads();
  }
  const float inv = 1.0f / (red[0] + 1e-8f);
  float* Prow = P + (size_t)i * N_TOK;
#pragma unroll
  for (int r = 0; r < 4; ++r) {
    g[r].x *= inv; g[r].y *= inv; g[r].z *= inv; g[r].w *= inv;
    *(float4*)&Prow[r * 1024 + t * 4] = g[r];
  }
}

// ---------------------------------------------------------------------------
extern "C" void kernel_launch(void* const* d_in, const int* in_sizes, int n_in,
                              void* d_out, int out_size, void* d_ws,
                              size_t ws_size, hipStream_t stream) {
  const float* x = (const float*)d_in[0];
  const float* Wq = (const float*)d_in[1];
  const float* Wk = (const float*)d_in[2];
  const float* Wv = (const float*)d_in[3];
  const float* Ws = (const float*)d_in[4];

  float* out = (float*)d_out;
  float* Z = out;                        // [4096, 512]   fp32
  float* Pout = Z + (size_t)N_TOK * DM;  // [4096, 4096]  fp32
  float* S = Pout + (size_t)N_TOK * N_TOK;

  const size_t E = (size_t)N_TOK * DM;  // 2M elements

  // ws layout: x16 (4MB), Wc16 (1.5MB), sg (16KB), stats (1MB), staging
  _Float16* x16 = (_Float16*)d_ws;
  _Float16* Wc16 = x16 + E;
  float* sg = (float*)(Wc16 + 3 * DM * DM);
  float2* pstats = (float2*)(sg + 4096);  // [4096][32] (m,l) partials
  _Float16* stage = (_Float16*)(pstats + (size_t)N_TOK * 32);

  // staging need: Q16,K16,VT16 (3*E) + Sc16 (N*N) fp16
  const size_t stage_bytes = (3 * E + (size_t)N_TOK * N_TOK) * sizeof(_Float16);
  const size_t base_bytes = (size_t)((char*)stage - (char*)d_ws);
  const bool ws_ok = ws_size >= base_bytes + stage_bytes;

  _Float16* Q16 = ws_ok ? stage : (_Float16*)Pout;
  _Float16* K16 = Q16 + E;
  _Float16* VT16 = K16 + E;
  _Float16* Sc16 = VT16 + E;  // [4096 x 4096] fp16 raw scaled scores

  const dim3 blk(256);
  const float qk_scale = 1.0f / sqrtf((float)DM);

  // 1. pack x->fp16 + sigma + pack W->fp16 (fused)
  pack_sigma<<<2816, blk, 0, stream>>>(x, Wq, Wk, Wv, Ws, x16, Wc16, sg);

  // 2. fused QKV projection -> Q16, K16, VT16 (V transposed in-epilogue)
  gemm_pipe<128, 128, 32, 16, 1><<<dim3(12, 32), blk, 0, stream>>>(
      x16, DM, Wc16, DM, 1.0f, Q16, K16, VT16, nullptr);

  // 3. raw scores fp16 = Q @ K^T / sqrt(D)  +  per-(row, colblock) (m,l)
  gemm_pipe<256, 128, 32, 16, 3><<<dim3(32, 16), blk, 0, stream>>>(
      Q16, DM, K16, DM, qk_scale, Sc16, nullptr, nullptr, pstats);

  // 4. mega tail: Z = softmax(Sc) @ V  +  S fp32  +  P rows
  if (ws_ok) {
    sv_fused<1><<<dim3(1536), blk, 0, stream>>>(Sc16, pstats, VT16, Z, S, sg,
                                                Pout);
  } else {
    sv_fused<0><<<dim3(512), blk, 0, stream>>>(Sc16, pstats, VT16, Z, S,
                                               nullptr, nullptr);
    tailP<<<N_TOK, blk, 0, stream>>>(sg, Pout);
  }
}

// Round 4
// 272.335 us; speedup vs baseline: 1.0096x; 1.0096x over previous
//
#include <hip/hip_runtime.h>
#include <math.h>

#define N_TOK 4096
#define DM 512

typedef _Float16 f16x8 __attribute__((ext_vector_type(8)));
typedef _Float16 f16x4 __attribute__((ext_vector_type(4)));
typedef float f32x4 __attribute__((ext_vector_type(4)));

__device__ __forceinline__ void async_ld16(const ushort* g, ushort* l) {
  __builtin_amdgcn_global_load_lds(
      (const __attribute__((address_space(1))) void*)g,
      (__attribute__((address_space(3))) void*)l, 16, 0, 0);
}

template <int N>
__device__ __forceinline__ void vm_wait() {
  asm volatile("s_waitcnt vmcnt(%0)" ::"i"(N) : "memory");
}

// ---------------------------------------------------------------------------
// Fused pack + sigma.
// blocks [0,2048): pack x (1024 elems = rows 2b,2b+1) and compute sigma rows
// blocks [2048,2816): pack Wq|Wk|Wv into concatenated Wc16
// ---------------------------------------------------------------------------
__global__ __launch_bounds__(256) void pack_sigma(
    const float* __restrict__ x, const float* __restrict__ Wq,
    const float* __restrict__ Wk, const float* __restrict__ Wv,
    const float* __restrict__ Ws, _Float16* __restrict__ x16,
    _Float16* __restrict__ Wc16, float* __restrict__ sg) {
  const int b = blockIdx.x;
  const int t = threadIdx.x;
  if (b < 2048) {
    int i = b * 1024 + t * 4;
    float4 v = *(const float4*)&x[i];
    f16x4 o;
    o.x = (_Float16)v.x; o.y = (_Float16)v.y;
    o.z = (_Float16)v.z; o.w = (_Float16)v.w;
    *(f16x4*)&x16[i] = o;
    // sigma: threads [0,128) -> row 2b, [128,256) -> row 2b+1
    int col = (t * 4) & 511;
    float4 w = *(const float4*)&Ws[col];
    float p = v.x * w.x + v.y * w.y + v.z * w.z + v.w * w.w;
    __shared__ float red[256];
    red[t] = p;
    __syncthreads();
    int lt = t & 127;
    for (int off = 64; off > 0; off >>= 1) {
      if (lt < off) red[t] += red[t + off];
      __syncthreads();
    }
    if (lt == 0) {
      float s = red[t];
      sg[2 * b + (t >> 7)] = fminf(fmaxf(s, 0.001f), 1.0f);
    }
  } else {
    int e = (b - 2048) * 1024 + t * 4;
    const float* src;
    int le = e & (DM * DM - 1);
    if (e < DM * DM) src = Wq + le;
    else if (e < 2 * DM * DM) src = Wk + le;
    else src = Wv + le;
    float4 v = *(const float4*)src;
    f16x4 o;
    o.x = (_Float16)v.x; o.y = (_Float16)v.y;
    o.z = (_Float16)v.z; o.w = (_Float16)v.w;
    *(f16x4*)&Wc16[e] = o;
  }
}

// ---------------------------------------------------------------------------
// 3-deep pipelined fp16 MFMA NT GEMM: C[m,n] = scale * sum_k A[m,k]*B[n,k]
// 256 thr = 4 waves in 2x2 grid; wave tile (BM/2)x(BN/2).
// 3 LDS buffers; counted vmcnt, raw s_barrier (R2-verified).
// EPI=1: QKV fused (N=1536): region bn>>9: 0->D0 (Q16), 1->D1 (K16),
//        2-> LDS-transpose -> D2 = VT16 [512][4096]  (V16 never materialized)
// EPI=3: raw scores: D0[gr*N_TOK+gc] = (f16)(acc*scale), PLUS per-row
//        softmax partials over this block's 128 cols:
//        Part[row*32 + blockIdx.x] = (m_b, l_b)  (float2)
// ---------------------------------------------------------------------------
template <int BM, int BN, int BK, int NT, int EPI>
__global__ __launch_bounds__(256) void gemm_pipe(
    const _Float16* __restrict__ A, int lda, const _Float16* __restrict__ B,
    int ldb, float scale, _Float16* __restrict__ D0,
    _Float16* __restrict__ D1, _Float16* __restrict__ D2,
    float2* __restrict__ Part) {
  constexpr int TB = (BM + BN) * BK;  // f16 per LDS buffer
  constexpr int ACH = BM * BK / 8;    // A 16B-chunks per tile
  constexpr int BCH = BN * BK / 8;
  constexpr int L = (ACH + BCH) / 256;  // global_load_lds per thread per tile
  constexpr int MI = BM / 32;
  constexpr int NJ = BN / 32;
  __shared__ _Float16 lds[3 * TB];
  const int t = threadIdx.x;

  const int w = t >> 6, Ln = t & 63;
  const int wm = (w >> 1) * (BM / 2), wn = (w & 1) * (BN / 2);
  const int row = Ln & 15, quad = Ln >> 4;
  const int bm = blockIdx.y * BM, bn = blockIdx.x * BN;

  f32x4 acc[MI][NJ] = {{}};

  const ushort* gp[L];
#pragma unroll
  for (int k = 0; k < L; ++k) {
    int c = t + k * 256;
    if (c < ACH) {
      int r = c / (BK / 8), c8 = c % (BK / 8);
      gp[k] = (const ushort*)(A + (size_t)(bm + r) * lda + c8 * 8);
    } else {
      int cb = c - ACH;
      int r = cb / (BK / 8), c8 = cb % (BK / 8);
      gp[k] = (const ushort*)(B + (size_t)(bn + r) * ldb + c8 * 8);
    }
  }

  auto stage = [&](int buf) {
    _Float16* dst = lds + buf * TB;
#pragma unroll
    for (int k = 0; k < L; ++k) {
      async_ld16(gp[k], (ushort*)(dst + (t + k * 256) * 8));
      gp[k] += BK;
    }
  };

  stage(0);
  stage(1);

  for (int tt = 0; tt < NT; ++tt) {
    const int cur = tt % 3;
    if (tt + 2 < NT) stage((tt + 2) % 3);
    if (tt < NT - 2) vm_wait<2 * L>();
    else if (tt == NT - 2) vm_wait<L>();
    else vm_wait<0>();
    __builtin_amdgcn_s_barrier();

    const _Float16* Ah = lds + cur * TB;
    const _Float16* Bh = Ah + BM * BK;
    f16x8 af[BK / 32][MI], bf[BK / 32][NJ];
#pragma unroll
    for (int kk = 0; kk < BK / 32; ++kk) {
#pragma unroll
      for (int i = 0; i < MI; ++i)
        af[kk][i] =
            *(const f16x8*)&Ah[(wm + i * 16 + row) * BK + kk * 32 + quad * 8];
#pragma unroll
      for (int j = 0; j < NJ; ++j)
        bf[kk][j] =
            *(const f16x8*)&Bh[(wn + j * 16 + row) * BK + kk * 32 + quad * 8];
    }
#pragma unroll
    for (int kk = 0; kk < BK / 32; ++kk)
#pragma unroll
      for (int i = 0; i < MI; ++i)
#pragma unroll
        for (int j = 0; j < NJ; ++j)
          acc[i][j] = __builtin_amdgcn_mfma_f32_16x16x32_f16(
              af[kk][i], bf[kk][j], acc[i][j], 0, 0, 0);

    asm volatile("s_waitcnt lgkmcnt(0)" ::: "memory");
    __builtin_amdgcn_s_barrier();
  }

  // epilogue: C/D layout col = lane&15, row = quad*4 + reg
  if constexpr (EPI == 1) {
    const int region = bn >> 9;  // uniform per block
    if (region < 2) {
      _Float16* D = (region == 0) ? D0 : D1;
#pragma unroll
      for (int i = 0; i < MI; ++i)
#pragma unroll
        for (int j = 0; j < NJ; ++j)
#pragma unroll
          for (int r = 0; r < 4; ++r) {
            int gr = bm + wm + i * 16 + quad * 4 + r;
            int nn = (bn & 511) + wn + j * 16 + row;
            D[(size_t)gr * 512 + nn] = (_Float16)acc[i][j][r];
          }
    } else {
      // V region: transpose via LDS, write VT16[nn][token] coalesced.
      _Float16* T = lds;  // [128][136] f16 = 34 KB (pipeline done, lds free)
#pragma unroll
      for (int i = 0; i < MI; ++i)
#pragma unroll
        for (int j = 0; j < NJ; ++j) {
          int nn = wn + j * 16 + row;
          int gr0 = wm + i * 16 + quad * 4;
          f16x4 v;
          v.x = (_Float16)acc[i][j][0]; v.y = (_Float16)acc[i][j][1];
          v.z = (_Float16)acc[i][j][2]; v.w = (_Float16)acc[i][j][3];
          *(f16x4*)&T[nn * 136 + gr0] = v;
        }
      __syncthreads();
#pragma unroll
      for (int c = 0; c < 8; ++c) {
        int cc = t + c * 256;        // 2048 chunks
        int nn = cc >> 4;            // 0..127
        int g8 = (cc & 15) * 8;      // 0..120
        f16x8 v = *(const f16x8*)&T[nn * 136 + g8];
        *(f16x8*)&D2[(size_t)((bn & 511) + nn) * 4096 + bm + g8] = v;
      }
    }
  } else {
    // EPI==3: raw scores + per-row (m,l) partials over this block's cols
    float2* Ml = (float2*)lds;  // [2][BM]  (lds free after final barrier)
#pragma unroll
    for (int i = 0; i < MI; ++i)
#pragma unroll
      for (int r = 0; r < 4; ++r) {
        float sv[NJ];
        int gr = bm + wm + i * 16 + quad * 4 + r;
#pragma unroll
        for (int j = 0; j < NJ; ++j) {
          _Float16 h = (_Float16)(acc[i][j][r] * scale);
          D0[(size_t)gr * N_TOK + bn + wn + j * 16 + row] = h;
          sv[j] = (float)h;  // stats from fp16-rounded values (bit-compat)
        }
        float m = sv[0];
#pragma unroll
        for (int j = 1; j < NJ; ++j) m = fmaxf(m, sv[j]);
#pragma unroll
        for (int off = 1; off < 16; off <<= 1)
          m = fmaxf(m, __shfl_xor(m, off));
        float se = 0.f;
#pragma unroll
        for (int j = 0; j < NJ; ++j) se += __expf(sv[j] - m);
#pragma unroll
        for (int off = 1; off < 16; off <<= 1) se += __shfl_xor(se, off);
        if (row == 0) {
          int rb = wm + i * 16 + quad * 4 + r;  // 0..BM-1
          Ml[(w & 1) * BM + rb] = make_float2(m, se);
        }
      }
    __syncthreads();
    // combine the two col-half waves, write global partials
    {
      float2 a = Ml[t];
      float2 b2 = Ml[BM + t];
      float m = fmaxf(a.x, b2.x);
      float l = a.y * __expf(a.x - m) + b2.y * __expf(b2.x - m);
      Part[(size_t)(bm + t) * 32 + blockIdx.x] = make_float2(m, l);
    }
  }
}

// ---------------------------------------------------------------------------
// Normalize pass (+ optional fused P rows):
//  b in [0,4096)          : row b: combine stats via shfl butterfly,
//                           S[b,:] = exp(s-m)/l fp32, p16 in place into Sc.
//  b in [4096,5120)       : P rows (4 each)   [WITH_P only]
// Pure-BW kernel, tiny LDS -> high occupancy.
// ---------------------------------------------------------------------------
template <int WITH_P>
__global__ __launch_bounds__(256) void normalize_kernel(
    const float2* __restrict__ stats, _Float16* __restrict__ Sc,
    float* __restrict__ S, const float* __restrict__ sigma,
    float* __restrict__ P) {
  const int t = threadIdx.x;
  const int b = blockIdx.x;

  if (WITH_P && b >= N_TOK) {
    __shared__ float red[4];
    const int pidx = b - N_TOK;  // 0..1023
    const int wv = t >> 6, lane = t & 63;
#pragma unroll 1
    for (int rr = 0; rr < 4; ++rr) {
      const int i = pidx * 4 + rr;
      const float sgv = sigma[i];
      const float inv2 = -0.5f / (sgv * sgv);
      const float cc = rsqrtf(6.283185307179586f * sgv);
      float4 g[4];
      float sum = 0.f;
#pragma unroll
      for (int r = 0; r < 4; ++r) {
        int j = r * 1024 + t * 4;
        float d0 = (float)(i - j);
        float d1 = d0 - 1.f, d2 = d0 - 2.f, d3 = d0 - 3.f;
        g[r].x = __expf(inv2 * d0 * d0) * cc;
        g[r].y = __expf(inv2 * d1 * d1) * cc;
        g[r].z = __expf(inv2 * d2 * d2) * cc;
        g[r].w = __expf(inv2 * d3 * d3) * cc;
        sum += g[r].x + g[r].y + g[r].z + g[r].w;
      }
#pragma unroll
      for (int off = 32; off > 0; off >>= 1) sum += __shfl_xor(sum, off);
      if (lane == 0) red[wv] = sum;
      __syncthreads();
      const float inv = 1.0f / (red[0] + red[1] + red[2] + red[3] + 1e-8f);
      float* Prow = P + (size_t)i * N_TOK;
#pragma unroll
      for (int r = 0; r < 4; ++r) {
        g[r].x *= inv; g[r].y *= inv; g[r].z *= inv; g[r].w *= inv;
        *(float4*)&Prow[r * 1024 + t * 4] = g[r];
      }
      __syncthreads();
    }
    return;
  }

  // ---- normalize row b ----
  // every thread combines the row's 32 (m,l) partials via butterfly within
  // its 32-lane group (lanes>=32 hold identical copies -> identical result)
  float2 pr = stats[(size_t)b * 32 + (t & 31)];
  float m = pr.x, l = pr.y;
#pragma unroll
  for (int off = 1; off < 32; off <<= 1) {
    float mo = __shfl_xor(m, off);
    float lo = __shfl_xor(l, off);
    float nm = fmaxf(m, mo);
    l = l * __expf(m - nm) + lo * __expf(mo - nm);
    m = nm;
  }
  const float linv = 1.0f / l;

  _Float16* src = Sc + (size_t)b * N_TOK + t * 16;
  float* dst = S + (size_t)b * N_TOK + t * 16;
  f16x8 h0 = *(const f16x8*)src;
  f16x8 h1 = *(const f16x8*)(src + 8);
  float e[16];
#pragma unroll
  for (int k = 0; k < 8; ++k) e[k] = __expf((float)h0[k] - m) * linv;
#pragma unroll
  for (int k = 0; k < 8; ++k) e[8 + k] = __expf((float)h1[k] - m) * linv;
#pragma unroll
  for (int q = 0; q < 4; ++q) {
    float4 o;
    o.x = e[q * 4]; o.y = e[q * 4 + 1]; o.z = e[q * 4 + 2]; o.w = e[q * 4 + 3];
    *(float4*)(dst + q * 4) = o;
  }
  f16x8 p0, p1;
#pragma unroll
  for (int k = 0; k < 8; ++k) {
    p0[k] = (_Float16)e[k];
    p1[k] = (_Float16)e[8 + k];
  }
  *(f16x8*)src = p0;
  *(f16x8*)(src + 8) = p1;
}

// ---------------------------------------------------------------------------
// SV GEMM: Z[64x128 tile] = p16 @ VT16. 3-deep pipeline, split-panel LDS
// ([2][rows][32], 64B stride -> conflict-free ds_read_b128). 256 blocks.
// ---------------------------------------------------------------------------
__global__ __launch_bounds__(256) void sv_gemm(const _Float16* __restrict__ A,
                                               const _Float16* __restrict__ B,
                                               float* __restrict__ Z) {
  constexpr int BK = 64, NT = N_TOK / BK;
  constexpr int TB = (64 + 128) * BK;  // 12288 f16 per buffer
  __shared__ _Float16 lds[3 * TB];     // 72 KB
  const int t = threadIdx.x;
  const int w = t >> 6, Ln = t & 63;
  const int wm = (w >> 1) * 32, wn = (w & 1) * 64;
  const int row = Ln & 15, quad = Ln >> 4;
  const int bm = (blockIdx.x >> 2) * 64, bn = (blockIdx.x & 3) * 128;

  f32x4 acc[2][4] = {{}};

  const int rA = t >> 2, oA = (t & 3) * 8;  // rA in [0,64)
  const ushort* ga = (const ushort*)(A + (size_t)(bm + rA) * N_TOK + oA);
  const ushort* gb0 = (const ushort*)(B + (size_t)(bn + rA) * N_TOK + oA);
  const ushort* gb1 = (const ushort*)(B + (size_t)(bn + rA + 64) * N_TOK + oA);

  auto stage = [&](int buf) {
    _Float16* Ah = lds + buf * TB;
    _Float16* Bh = Ah + 64 * BK;
    async_ld16(ga, (ushort*)(Ah + t * 8));              // A panel0
    async_ld16(ga + 32, (ushort*)(Ah + 2048 + t * 8));  // A panel1
    async_ld16(gb0, (ushort*)(Bh + t * 8));             // B p0 r0-63
    async_ld16(gb1, (ushort*)(Bh + (t + 256) * 8));     // B p0 r64-127
    async_ld16(gb0 + 32, (ushort*)(Bh + 4096 + t * 8));          // B p1
    async_ld16(gb1 + 32, (ushort*)(Bh + 4096 + (t + 256) * 8));  // B p1
    ga += 64; gb0 += 64; gb1 += 64;
  };

  stage(0);
  stage(1);

  for (int tt = 0; tt < NT; ++tt) {
    const int cur = tt % 3;
    if (tt + 2 < NT) stage((tt + 2) % 3);
    if (tt < NT - 2) vm_wait<12>();
    else if (tt == NT - 2) vm_wait<6>();
    else vm_wait<0>();
    __builtin_amdgcn_s_barrier();

    const _Float16* Ah = lds + cur * TB;
    const _Float16* Bh = Ah + 64 * BK;
    f16x8 af[2][2], bf[2][4];
#pragma unroll
    for (int kk = 0; kk < 2; ++kk) {
#pragma unroll
      for (int i = 0; i < 2; ++i)
        af[kk][i] =
            *(const f16x8*)&Ah[kk * 2048 + (wm + i * 16 + row) * 32 + quad * 8];
#pragma unroll
      for (int j = 0; j < 4; ++j)
        bf[kk][j] =
            *(const f16x8*)&Bh[kk * 4096 + (wn + j * 16 + row) * 32 + quad * 8];
    }
#pragma unroll
    for (int kk = 0; kk < 2; ++kk)
#pragma unroll
      for (int i = 0; i < 2; ++i)
#pragma unroll
        for (int j = 0; j < 4; ++j)
          acc[i][j] = __builtin_amdgcn_mfma_f32_16x16x32_f16(
              af[kk][i], bf[kk][j], acc[i][j], 0, 0, 0);

    asm volatile("s_waitcnt lgkmcnt(0)" ::: "memory");
    __builtin_amdgcn_s_barrier();
  }

#pragma unroll
  for (int i = 0; i < 2; ++i)
#pragma unroll
    for (int j = 0; j < 4; ++j)
#pragma unroll
      for (int r = 0; r < 4; ++r) {
        int gr = bm + wm + i * 16 + quad * 4 + r;
        int gc = bn + wn + j * 16 + row;
        Z[(size_t)gr * DM + gc] = acc[i][j][r];
      }
}

// ---------------------------------------------------------------------------
// Fallback P-only tail (used only if ws too small to relocate staging)
// ---------------------------------------------------------------------------
__global__ __launch_bounds__(256) void tailP(const float* __restrict__ sigma,
                                             float* __restrict__ P) {
  __shared__ float red[256];
  const int t = threadIdx.x;
  const int i = blockIdx.x;
  const float sg = sigma[i];
  const float inv2 = -0.5f / (sg * sg);
  const float c = rsqrtf(6.283185307179586f * sg);
  float4 g[4];
  float sum = 0.f;
#pragma unroll
  for (int r = 0; r < 4; ++r) {
    int j = r * 1024 + t * 4;
    float d0 = (float)(i - j);
    float d1 = d0 - 1.f, d2 = d0 - 2.f, d3 = d0 - 3.f;
    g[r].x = __expf(inv2 * d0 * d0) * c;
    g[r].y = __expf(inv2 * d1 * d1) * c;
    g[r].z = __expf(inv2 * d2 * d2) * c;
    g[r].w = __expf(inv2 * d3 * d3) * c;
    sum += g[r].x + g[r].y + g[r].z + g[r].w;
  }
  red[t] = sum;
  __syncthreads();
  for (int off = 128; off > 0; off >>= 1) {
    if (t < off) red[t] += red[t + off];
    __syncthreads();
  }
  const float inv = 1.0f / (red[0] + 1e-8f);
  float* Prow = P + (size_t)i * N_TOK;
#pragma unroll
  for (int r = 0; r < 4; ++r) {
    g[r].x *= inv; g[r].y *= inv; g[r].z *= inv; g[r].w *= inv;
    *(float4*)&Prow[r * 1024 + t * 4] = g[r];
  }
}

// ---------------------------------------------------------------------------
extern "C" void kernel_launch(void* const* d_in, const int* in_sizes, int n_in,
                              void* d_out, int out_size, void* d_ws,
                              size_t ws_size, hipStream_t stream) {
  const float* x = (const float*)d_in[0];
  const float* Wq = (const float*)d_in[1];
  const float* Wk = (const float*)d_in[2];
  const float* Wv = (const float*)d_in[3];
  const float* Ws = (const float*)d_in[4];

  float* out = (float*)d_out;
  float* Z = out;                        // [4096, 512]   fp32
  float* Pout = Z + (size_t)N_TOK * DM;  // [4096, 4096]  fp32
  float* S = Pout + (size_t)N_TOK * N_TOK;

  const size_t E = (size_t)N_TOK * DM;  // 2M elements

  // ws layout: x16 (4MB), Wc16 (1.5MB), sg (16KB), stats (1MB), staging
  _Float16* x16 = (_Float16*)d_ws;
  _Float16* Wc16 = x16 + E;
  float* sg = (float*)(Wc16 + 3 * DM * DM);
  float2* pstats = (float2*)(sg + 4096);  // [4096][32] (m,l) partials
  _Float16* stage = (_Float16*)(pstats + (size_t)N_TOK * 32);

  // staging need: Q16,K16,VT16 (3*E) + Sc16 (N*N) fp16
  const size_t stage_bytes = (3 * E + (size_t)N_TOK * N_TOK) * sizeof(_Float16);
  const size_t base_bytes = (size_t)((char*)stage - (char*)d_ws);
  const bool ws_ok = ws_size >= base_bytes + stage_bytes;

  _Float16* Q16 = ws_ok ? stage : (_Float16*)Pout;
  _Float16* K16 = Q16 + E;
  _Float16* VT16 = K16 + E;
  _Float16* Sc16 = VT16 + E;  // [4096 x 4096] fp16 raw scaled scores -> p16

  const dim3 blk(256);
  const float qk_scale = 1.0f / sqrtf((float)DM);

  // 1. pack x->fp16 + sigma + pack W->fp16 (fused)
  pack_sigma<<<2816, blk, 0, stream>>>(x, Wq, Wk, Wv, Ws, x16, Wc16, sg);

  // 2. fused QKV projection -> Q16, K16, VT16 (V transposed in-epilogue)
  gemm_pipe<128, 128, 32, 16, 1><<<dim3(12, 32), blk, 0, stream>>>(
      x16, DM, Wc16, DM, 1.0f, Q16, K16, VT16, nullptr);

  // 3. raw scores fp16 = Q @ K^T / sqrt(D)  +  per-(row, colblock) (m,l)
  gemm_pipe<256, 128, 32, 16, 3><<<dim3(32, 16), blk, 0, stream>>>(
      Q16, DM, K16, DM, qk_scale, Sc16, nullptr, nullptr, pstats);

  if (ws_ok) {
    // 4. normalize (S fp32 + p16 in place) + P rows fused (pure-BW dispatch)
    normalize_kernel<1><<<dim3(4096 + 1024), blk, 0, stream>>>(pstats, Sc16, S,
                                                               sg, Pout);
    // 5. Z = p16 @ V^T (pure GEMM, conflict-free split-panel LDS)
    sv_gemm<<<dim3(256), blk, 0, stream>>>(Sc16, VT16, Z);
  } else {
    normalize_kernel<0><<<dim3(4096), blk, 0, stream>>>(pstats, Sc16, S,
                                                        nullptr, nullptr);
    sv_gemm<<<dim3(256), blk, 0, stream>>>(Sc16, VT16, Z);
    tailP<<<N_TOK, blk, 0, stream>>>(sg, Pout);
  }
}

// Round 5
// 245.734 us; speedup vs baseline: 1.1189x; 1.1083x over previous
//
#include <hip/hip_runtime.h>
#include <math.h>

#define N_TOK 4096
#define DM 512

typedef _Float16 f16x8 __attribute__((ext_vector_type(8)));
typedef _Float16 f16x4 __attribute__((ext_vector_type(4)));
typedef float f32x4 __attribute__((ext_vector_type(4)));

__device__ __forceinline__ void async_ld16(const ushort* g, ushort* l) {
  __builtin_amdgcn_global_load_lds(
      (const __attribute__((address_space(1))) void*)g,
      (__attribute__((address_space(3))) void*)l, 16, 0, 0);
}

template <int N>
__device__ __forceinline__ void vm_wait() {
  asm volatile("s_waitcnt vmcnt(%0)" ::"i"(N) : "memory");
}

// ---------------------------------------------------------------------------
// Fused pack + sigma.
// blocks [0,2048): pack x (1024 elems = rows 2b,2b+1) and compute sigma rows
// blocks [2048,2816): pack Wq|Wk|Wv into concatenated Wc16
// ---------------------------------------------------------------------------
__global__ __launch_bounds__(256) void pack_sigma(
    const float* __restrict__ x, const float* __restrict__ Wq,
    const float* __restrict__ Wk, const float* __restrict__ Wv,
    const float* __restrict__ Ws, _Float16* __restrict__ x16,
    _Float16* __restrict__ Wc16, float* __restrict__ sg) {
  const int b = blockIdx.x;
  const int t = threadIdx.x;
  if (b < 2048) {
    int i = b * 1024 + t * 4;
    float4 v = *(const float4*)&x[i];
    f16x4 o;
    o.x = (_Float16)v.x; o.y = (_Float16)v.y;
    o.z = (_Float16)v.z; o.w = (_Float16)v.w;
    *(f16x4*)&x16[i] = o;
    // sigma: threads [0,128) -> row 2b, [128,256) -> row 2b+1
    int col = (t * 4) & 511;
    float4 w = *(const float4*)&Ws[col];
    float p = v.x * w.x + v.y * w.y + v.z * w.z + v.w * w.w;
    __shared__ float red[256];
    red[t] = p;
    __syncthreads();
    int lt = t & 127;
    for (int off = 64; off > 0; off >>= 1) {
      if (lt < off) red[t] += red[t + off];
      __syncthreads();
    }
    if (lt == 0) {
      float s = red[t];
      sg[2 * b + (t >> 7)] = fminf(fmaxf(s, 0.001f), 1.0f);
    }
  } else {
    int e = (b - 2048) * 1024 + t * 4;
    const float* src;
    int le = e & (DM * DM - 1);
    if (e < DM * DM) src = Wq + le;
    else if (e < 2 * DM * DM) src = Wk + le;
    else src = Wv + le;
    float4 v = *(const float4*)src;
    f16x4 o;
    o.x = (_Float16)v.x; o.y = (_Float16)v.y;
    o.z = (_Float16)v.z; o.w = (_Float16)v.w;
    *(f16x4*)&Wc16[e] = o;
  }
}

// ---------------------------------------------------------------------------
// 3-deep pipelined fp16 MFMA NT GEMM: C[m,n] = scale * sum_k A[m,k]*B[n,k]
// 256 thr = 4 waves in 2x2 grid; wave tile (BM/2)x(BN/2).
// 3 LDS buffers; tile t+2 staged via global_load_lds while tile t computes;
// counted s_waitcnt vmcnt(2L) + raw s_barrier (never a full vmcnt(0) drain
// in steady state) => HBM latency hidden by ILP, works at 1 block/CU.
// EPI=1: QKV fused (N=1536): region bn>>9 -> D0(Q16)/D1(K16)/D2(V16), fp16
// EPI=3: fp16 out: D0[gr*N_TOK+gc] = (f16)(acc*scale)      (raw scores)
// EPI=2: fp32 out: Cf[gr*DM+gc] = acc; FUSE_P: blocks y>=64 emit P rows.
//        EPI=2 GEMM region is XCD-swizzled: same-bm blocks land on one XCD
//        (A-panel fetched once per XCD; per-XCD distinct set 18MB -> 8MB).
// ---------------------------------------------------------------------------
template <int BM, int BN, int BK, int NT, int EPI, int FUSE_P>
__global__ __launch_bounds__(256) void gemm_pipe(
    const _Float16* __restrict__ A, int lda, const _Float16* __restrict__ B,
    int ldb, float scale, float* __restrict__ Cf, _Float16* __restrict__ D0,
    _Float16* __restrict__ D1, _Float16* __restrict__ D2,
    const float* __restrict__ sigma, float* __restrict__ P) {
  constexpr int TB = (BM + BN) * BK;  // f16 per LDS buffer
  constexpr int ACH = BM * BK / 8;    // A 16B-chunks per tile
  constexpr int BCH = BN * BK / 8;
  constexpr int L = (ACH + BCH) / 256;  // global_load_lds per thread per tile
  constexpr int MI = BM / 32;           // row frags per wave (wave = BM/2 rows)
  constexpr int NJ = BN / 32;
  __shared__ _Float16 lds[3 * TB];
  const int t = threadIdx.x;

  if (FUSE_P && blockIdx.y >= 64) {
    // ---------------- P rows (4 per block), overlaps the GEMM ----------------
    float* red = (float*)lds;
    const int pidx = (blockIdx.y - 64) * 4 + blockIdx.x;  // 0..1023
    const int w = t >> 6, lane = t & 63;
#pragma unroll 1
    for (int rr = 0; rr < 4; ++rr) {
      const int i = pidx * 4 + rr;
      const float sgv = sigma[i];
      const float inv2 = -0.5f / (sgv * sgv);
      const float cc = rsqrtf(6.283185307179586f * sgv);
      float4 g[4];
      float sum = 0.f;
#pragma unroll
      for (int r = 0; r < 4; ++r) {
        int j = r * 1024 + t * 4;
        float d0 = (float)(i - j);
        float d1 = d0 - 1.f, d2 = d0 - 2.f, d3 = d0 - 3.f;
        g[r].x = __expf(inv2 * d0 * d0) * cc;
        g[r].y = __expf(inv2 * d1 * d1) * cc;
        g[r].z = __expf(inv2 * d2 * d2) * cc;
        g[r].w = __expf(inv2 * d3 * d3) * cc;
        sum += g[r].x + g[r].y + g[r].z + g[r].w;
      }
#pragma unroll
      for (int off = 32; off > 0; off >>= 1) sum += __shfl_xor(sum, off);
      if (lane == 0) red[w] = sum;
      __syncthreads();
      const float inv = 1.0f / (red[0] + red[1] + red[2] + red[3] + 1e-8f);
      float* Prow = P + (size_t)i * N_TOK;
#pragma unroll
      for (int r = 0; r < 4; ++r) {
        g[r].x *= inv; g[r].y *= inv; g[r].z *= inv; g[r].w *= inv;
        *(float4*)&Prow[r * 1024 + t * 4] = g[r];
      }
      __syncthreads();  // red[] reuse
    }
    return;
  }

  // ---------------- pipelined GEMM ----------------
  const int w = t >> 6, Ln = t & 63;
  const int wm = (w >> 1) * (BM / 2), wn = (w & 1) * (BN / 2);
  const int row = Ln & 15, quad = Ln >> 4;

  int bm, bn;
  if constexpr (EPI == 2) {
    // XCD-aware swizzle (bijective on [0,256)): xcd = lb&7 gets bm-panel
    // group [xcd*8, xcd*8+8) x all 4 bn -> A-panels fetched once per XCD.
    const int lb = blockIdx.x + 4 * blockIdx.y;
    const int xcd = lb & 7, idx = lb >> 3;
    bm = ((xcd << 3) | (idx >> 2)) * BM;
    bn = (idx & 3) * BN;
  } else {
    bm = blockIdx.y * BM;
    bn = blockIdx.x * BN;
  }

  f32x4 acc[MI][NJ] = {{}};

  // per-thread global pointers for the L staging loads (chunk = t + k*256)
  const ushort* gp[L];
#pragma unroll
  for (int k = 0; k < L; ++k) {
    int c = t + k * 256;
    if (c < ACH) {
      int r = c / (BK / 8), c8 = c % (BK / 8);
      gp[k] = (const ushort*)(A + (size_t)(bm + r) * lda + c8 * 8);
    } else {
      int cb = c - ACH;
      int r = cb / (BK / 8), c8 = cb % (BK / 8);
      gp[k] = (const ushort*)(B + (size_t)(bn + r) * ldb + c8 * 8);
    }
  }

  auto stage = [&](int buf) {
    _Float16* dst = lds + buf * TB;
#pragma unroll
    for (int k = 0; k < L; ++k) {
      async_ld16(gp[k], (ushort*)(dst + (t + k * 256) * 8));
      gp[k] += BK;  // ushort* += BK elems == BK f16
    }
  };

  stage(0);  // tile 0
  stage(1);  // tile 1  (2L outstanding)

  for (int tt = 0; tt < NT; ++tt) {
    const int cur = tt % 3;
    if (tt + 2 < NT) stage((tt + 2) % 3);  // 3L outstanding
    // wait until tile tt's L loads (the oldest) have landed:
    if (tt < NT - 2) vm_wait<2 * L>();
    else if (tt == NT - 2) vm_wait<L>();
    else vm_wait<0>();
    __builtin_amdgcn_s_barrier();

    const _Float16* Ah = lds + cur * TB;
    const _Float16* Bh = Ah + BM * BK;
    f16x8 af[BK / 32][MI], bf[BK / 32][NJ];
#pragma unroll
    for (int kk = 0; kk < BK / 32; ++kk) {
#pragma unroll
      for (int i = 0; i < MI; ++i)
        af[kk][i] =
            *(const f16x8*)&Ah[(wm + i * 16 + row) * BK + kk * 32 + quad * 8];
#pragma unroll
      for (int j = 0; j < NJ; ++j)
        bf[kk][j] =
            *(const f16x8*)&Bh[(wn + j * 16 + row) * BK + kk * 32 + quad * 8];
    }
#pragma unroll
    for (int kk = 0; kk < BK / 32; ++kk)
#pragma unroll
      for (int i = 0; i < MI; ++i)
#pragma unroll
        for (int j = 0; j < NJ; ++j)
          acc[i][j] = __builtin_amdgcn_mfma_f32_16x16x32_f16(
              af[kk][i], bf[kk][j], acc[i][j], 0, 0, 0);

    asm volatile("s_waitcnt lgkmcnt(0)" ::: "memory");
    __builtin_amdgcn_s_barrier();  // safe to overwrite buf[cur] next iter
  }

  // epilogue: C/D layout col = lane&15, row = quad*4 + reg
  if constexpr (EPI == 1) {
    const int region = bn >> 9;  // uniform per block
    _Float16* D = (region == 0) ? D0 : ((region == 1) ? D1 : D2);
#pragma unroll
    for (int i = 0; i < MI; ++i)
#pragma unroll
      for (int j = 0; j < NJ; ++j)
#pragma unroll
        for (int r = 0; r < 4; ++r) {
          int gr = bm + wm + i * 16 + quad * 4 + r;
          int nn = (bn & 511) + wn + j * 16 + row;
          D[(size_t)gr * 512 + nn] = (_Float16)acc[i][j][r];
        }
  } else if constexpr (EPI == 3) {
#pragma unroll
    for (int i = 0; i < MI; ++i)
#pragma unroll
      for (int j = 0; j < NJ; ++j)
#pragma unroll
        for (int r = 0; r < 4; ++r) {
          int gr = bm + wm + i * 16 + quad * 4 + r;
          int gc = bn + wn + j * 16 + row;
          D0[(size_t)gr * N_TOK + gc] = (_Float16)(acc[i][j][r] * scale);
        }
  } else {
#pragma unroll
    for (int i = 0; i < MI; ++i)
#pragma unroll
      for (int j = 0; j < NJ; ++j)
#pragma unroll
        for (int r = 0; r < 4; ++r) {
          int gr = bm + wm + i * 16 + quad * 4 + r;
          int gc = bn + wn + j * 16 + row;
          Cf[(size_t)gr * DM + gc] = acc[i][j][r];
        }
  }
}

// ---------------------------------------------------------------------------
// V16 [4096x512] fp16 -> VT16 [512][4096] fp16
// ---------------------------------------------------------------------------
__global__ __launch_bounds__(256) void transpose16(
    const _Float16* __restrict__ V16, _Float16* __restrict__ VT) {
  __shared__ _Float16 T[32][34];
  const int t = threadIdx.x;
  const int r = t >> 3, c4 = (t & 7) * 4;
  f16x4 v = *(const f16x4*)&V16[(size_t)(blockIdx.y * 32 + r) * 512 +
                                blockIdx.x * 32 + c4];
  T[r][c4] = v.x; T[r][c4 + 1] = v.y; T[r][c4 + 2] = v.z; T[r][c4 + 3] = v.w;
  __syncthreads();
  f16x4 o;
  o.x = T[c4][r]; o.y = T[c4 + 1][r]; o.z = T[c4 + 2][r]; o.w = T[c4 + 3][r];
  *(f16x4*)&VT[(size_t)(blockIdx.x * 32 + r) * 4096 + blockIdx.y * 32 + c4] = o;
}

// ---------------------------------------------------------------------------
// Softmax: read raw fp16 scores Sc (one row/block), fp32 math, write
// S fp32 (output) + softmaxed fp16 back into Sc in place.
// Butterfly version: per-wave shfl_xor reduce + 4-slot LDS combine
// (2 __syncthreads total vs 16 in the tree version).
// ---------------------------------------------------------------------------
__global__ __launch_bounds__(256) void softmax_kernel(
    _Float16* __restrict__ Sc, float* __restrict__ S) {
  __shared__ float red[8];
  const int t = threadIdx.x;
  const int w = t >> 6, lane = t & 63;
  _Float16* Srow16 = Sc + (size_t)blockIdx.x * N_TOK;
  float* Srow = S + (size_t)blockIdx.x * N_TOK;
  float f[16];
  float m = -INFINITY;
#pragma unroll
  for (int r = 0; r < 4; ++r) {
    f16x4 h = *(const f16x4*)&Srow16[r * 1024 + t * 4];
    f[r * 4 + 0] = (float)h.x; f[r * 4 + 1] = (float)h.y;
    f[r * 4 + 2] = (float)h.z; f[r * 4 + 3] = (float)h.w;
    m = fmaxf(m, fmaxf(fmaxf(f[r * 4], f[r * 4 + 1]),
                       fmaxf(f[r * 4 + 2], f[r * 4 + 3])));
  }
#pragma unroll
  for (int off = 32; off > 0; off >>= 1) m = fmaxf(m, __shfl_xor(m, off));
  if (lane == 0) red[w] = m;
  __syncthreads();
  m = fmaxf(fmaxf(red[0], red[1]), fmaxf(red[2], red[3]));
  float sum = 0.f;
#pragma unroll
  for (int i = 0; i < 16; ++i) {
    f[i] = __expf(f[i] - m);
    sum += f[i];
  }
#pragma unroll
  for (int off = 32; off > 0; off >>= 1) sum += __shfl_xor(sum, off);
  if (lane == 0) red[4 + w] = sum;
  __syncthreads();
  const float inv = 1.0f / (red[4] + red[5] + red[6] + red[7]);
#pragma unroll
  for (int r = 0; r < 4; ++r) {
    float4 o;
    o.x = f[r * 4 + 0] * inv; o.y = f[r * 4 + 1] * inv;
    o.z = f[r * 4 + 2] * inv; o.w = f[r * 4 + 3] * inv;
    *(float4*)&Srow[r * 1024 + t * 4] = o;
    f16x4 h;
    h.x = (_Float16)o.x; h.y = (_Float16)o.y;
    h.z = (_Float16)o.z; h.w = (_Float16)o.w;
    *(f16x4*)&Srow16[r * 1024 + t * 4] = h;
  }
}

// ---------------------------------------------------------------------------
// Fallback P-only tail (used only if ws too small to relocate staging)
// ---------------------------------------------------------------------------
__global__ __launch_bounds__(256) void tailP(const float* __restrict__ sigma,
                                             float* __restrict__ P) {
  __shared__ float red[256];
  const int t = threadIdx.x;
  const int i = blockIdx.x;
  const float sg = sigma[i];
  const float inv2 = -0.5f / (sg * sg);
  const float c = rsqrtf(6.283185307179586f * sg);
  float4 g[4];
  float sum = 0.f;
#pragma unroll
  for (int r = 0; r < 4; ++r) {
    int j = r * 1024 + t * 4;
    float d0 = (float)(i - j);
    float d1 = d0 - 1.f, d2 = d0 - 2.f, d3 = d0 - 3.f;
    g[r].x = __expf(inv2 * d0 * d0) * c;
    g[r].y = __expf(inv2 * d1 * d1) * c;
    g[r].z = __expf(inv2 * d2 * d2) * c;
    g[r].w = __expf(inv2 * d3 * d3) * c;
    sum += g[r].x + g[r].y + g[r].z + g[r].w;
  }
  red[t] = sum;
  __syncthreads();
  for (int off = 128; off > 0; off >>= 1) {
    if (t < off) red[t] += red[t + off];
    __syncthreads();
  }
  const float inv = 1.0f / (red[0] + 1e-8f);
  float* Prow = P + (size_t)i * N_TOK;
#pragma unroll
  for (int r = 0; r < 4; ++r) {
    g[r].x *= inv; g[r].y *= inv; g[r].z *= inv; g[r].w *= inv;
    *(float4*)&Prow[r * 1024 + t * 4] = g[r];
  }
}

// ---------------------------------------------------------------------------
extern "C" void kernel_launch(void* const* d_in, const int* in_sizes, int n_in,
                              void* d_out, int out_size, void* d_ws,
                              size_t ws_size, hipStream_t stream) {
  const float* x = (const float*)d_in[0];
  const float* Wq = (const float*)d_in[1];
  const float* Wk = (const float*)d_in[2];
  const float* Wv = (const float*)d_in[3];
  const float* Ws = (const float*)d_in[4];

  float* out = (float*)d_out;
  float* Z = out;                        // [4096, 512]   fp32
  float* Pout = Z + (size_t)N_TOK * DM;  // [4096, 4096]  fp32
  float* S = Pout + (size_t)N_TOK * N_TOK;

  const size_t E = (size_t)N_TOK * DM;  // 2M elements

  // ws layout: x16 (4MB), Wc16 (1.5MB), sg (16KB), then fp16 staging
  _Float16* x16 = (_Float16*)d_ws;
  _Float16* Wc16 = x16 + E;
  float* sg = (float*)(Wc16 + 3 * DM * DM);
  _Float16* stage = (_Float16*)(sg + 4096);

  // staging need: Q16,K16,V16,VT16 (4*E) + Sc16 (N*N) fp16
  const size_t stage_bytes = (4 * E + (size_t)N_TOK * N_TOK) * sizeof(_Float16);
  const size_t base_bytes = (size_t)((char*)stage - (char*)d_ws);
  const bool ws_ok = ws_size >= base_bytes + stage_bytes;

  _Float16* Q16 = ws_ok ? stage : (_Float16*)Pout;
  _Float16* K16 = Q16 + E;
  _Float16* V16 = K16 + E;
  _Float16* VT16 = V16 + E;
  _Float16* Sc16 = VT16 + E;  // [4096 x 4096] fp16: raw scores -> p16

  const dim3 blk(256);
  const float qk_scale = 1.0f / sqrtf((float)DM);

  // 1. pack x->fp16 + sigma + pack W->fp16 (fused)
  pack_sigma<<<2816, blk, 0, stream>>>(x, Wq, Wk, Wv, Ws, x16, Wc16, sg);

  // 2. fused QKV projection: [4096x1536] = x16 @ Wcat^T -> Q16,K16,V16 fp16
  gemm_pipe<128, 128, 32, 16, 1, 0><<<dim3(12, 32), blk, 0, stream>>>(
      x16, DM, Wc16, DM, 1.0f, nullptr, Q16, K16, V16, nullptr, nullptr);

  // 3. V -> V^T fp16
  transpose16<<<dim3(16, 128), blk, 0, stream>>>(V16, VT16);

  // 4. raw scores fp16 = Q @ K^T / sqrt(D)
  gemm_pipe<256, 128, 32, 16, 3, 0><<<dim3(32, 16), blk, 0, stream>>>(
      Q16, DM, K16, DM, qk_scale, nullptr, Sc16, nullptr, nullptr, nullptr,
      nullptr);

  // 5. softmax: Sc16 -> S fp32 + p16 fp16 (in place), butterfly reduce
  softmax_kernel<<<N_TOK, blk, 0, stream>>>(Sc16, S);

  // 6. Z = p16 @ V^T (pipelined, XCD-swizzled) + P rows co-resident
  if (ws_ok) {
    gemm_pipe<64, 128, 64, 64, 2, 1><<<dim3(4, 64 + 256), blk, 0, stream>>>(
        Sc16, N_TOK, VT16, N_TOK, 1.0f, Z, nullptr, nullptr, nullptr, sg, Pout);
  } else {
    gemm_pipe<64, 128, 64, 64, 2, 0><<<dim3(4, 64), blk, 0, stream>>>(
        Sc16, N_TOK, VT16, N_TOK, 1.0f, Z, nullptr, nullptr, nullptr, nullptr,
        nullptr);
    tailP<<<N_TOK, blk, 0, stream>>>(sg, Pout);
  }
}